// Round 2
// baseline (801.377 us; speedup 1.0000x reference)
//
#include <hip/hip_runtime.h>
#include <hip/hip_bf16.h>

using u16 = unsigned short;
using u32 = unsigned int;

typedef __bf16 bf16x8 __attribute__((ext_vector_type(8)));
typedef float  f32x4  __attribute__((ext_vector_type(4)));
typedef u32    u32x4  __attribute__((ext_vector_type(4)));

__device__ __forceinline__ float bflo(u32 u){ union { u32 u; float f; } c; c.u = u << 16;          return c.f; }
__device__ __forceinline__ float bfhi(u32 u){ union { u32 u; float f; } c; c.u = u & 0xffff0000u;  return c.f; }
__device__ __forceinline__ u16  f2bf(float f){
  union { float f; u32 u; } c; c.f = f;
  u32 u = c.u;
  return (u16)((u + 0x7fffu + ((u >> 16) & 1u)) >> 16); // RNE
}

__device__ __forceinline__ void gload_lds16(const void* g, void* l){
  __builtin_amdgcn_global_load_lds(
      (const __attribute__((address_space(1))) void*)g,
      (__attribute__((address_space(3))) void*)l, 16, 0, 0);
}

// ---------------- prep kernels ----------------

__global__ void count_deg_kernel(const int* __restrict__ dst, int E, int* __restrict__ cnt){
  int i = blockIdx.x * blockDim.x + threadIdx.x;
  if (i < E) atomicAdd(&cnt[dst[i]], 1);
}

__global__ void scan_kernel(const int* __restrict__ cnt, int N,
                            int* __restrict__ rowptr, int* __restrict__ cursor,
                            float* __restrict__ dis){
  __shared__ int sdata[1024];
  const int tid = threadIdx.x;
  int off = 0;
  for (int base = 0; base < N; base += 1024){
    int i = base + tid;
    int v = (i < N) ? cnt[i] : 0;
    sdata[tid] = v;
    __syncthreads();
    for (int s = 1; s < 1024; s <<= 1){
      int t = (tid >= s) ? sdata[tid - s] : 0;
      __syncthreads();
      sdata[tid] += t;
      __syncthreads();
    }
    if (i < N){
      int excl = off + sdata[tid] - v;
      rowptr[i] = excl;
      cursor[i] = excl;
      dis[i]    = rsqrtf((float)(v + 1)); // +1 self loop, deg >= 1
    }
    off += sdata[1023];
    __syncthreads();
  }
  if (tid == 0) rowptr[N] = off;
}

__global__ void fill_csr_kernel(const int* __restrict__ src, const int* __restrict__ dst,
                                int E, int* __restrict__ cursor, int* __restrict__ col){
  int i = blockIdx.x * blockDim.x + threadIdx.x;
  if (i < E){
    int d = dst[i];
    int p = atomicAdd(&cursor[d], 1);
    col[p] = src[i];
  }
}

__global__ void convert_x_kernel(const float* __restrict__ x, u32* __restrict__ xb,
                                 int n_real, int n_tot){
  int i8 = (blockIdx.x * blockDim.x + threadIdx.x) * 8;
  if (i8 >= n_tot) return;
  u32 q0, q1, q2, q3;
  if (i8 < n_real){ // n_real is a multiple of 8
    const f32x4* xp = (const f32x4*)(x + i8);
    f32x4 a = xp[0], b = xp[1];
    q0 = ((u32)f2bf(a[1]) << 16) | f2bf(a[0]);
    q1 = ((u32)f2bf(a[3]) << 16) | f2bf(a[2]);
    q2 = ((u32)f2bf(b[1]) << 16) | f2bf(b[0]);
    q3 = ((u32)f2bf(b[3]) << 16) | f2bf(b[2]);
  } else {
    q0 = q1 = q2 = q3 = 0u; // zero pad rows so GEMM needs no bounds checks
  }
  u32x4 q = {q0, q1, q2, q3};
  *(u32x4*)(xb + (i8 >> 1)) = q;
}

// Wt[l][n][k] = bf16(W[l][k][n])  -> GEMM reads B^T row-major along K
__global__ void convert_w_kernel(const float* __restrict__ W, u16* __restrict__ Wt, int total){
  int i = blockIdx.x * blockDim.x + threadIdx.x;
  if (i >= total) return;
  int k = i & 511, n = (i >> 9) & 511, l = i >> 18;
  Wt[i] = f2bf(W[(l << 18) | (k << 9) | n]);
}

// ---------------- GEMM: C[M][512] = A[M][512] * W  (B^T layout) ----------------
// BM=BN=128, BK=64, 256 threads (4 waves, 2x2), double-buffered global_load_lds.

__global__ __launch_bounds__(256) void gemm_kernel(const u16* __restrict__ A,
                                                   const u16* __restrict__ Bt,
                                                   u16* __restrict__ C){
  __shared__ u16 sA[2][128 * 64];
  __shared__ u16 sB[2][128 * 64];
  const int tid  = threadIdx.x;
  const int lane = tid & 63;
  const int wv   = tid >> 6;
  const int wm   = wv >> 1, wn = wv & 1;
  const int bm0  = blockIdx.x * 128;
  const int bn0  = blockIdx.y * 128;
  const int sr   = lane >> 3;        // row within 8-row stage group
  const int sc   = (lane & 7) << 3;  // k-offset (elements) within row

  f32x4 acc[4][4] = {};

  auto stage = [&](int bsel, int t){
    const int k0 = t * 64;
    #pragma unroll
    for (int i = 0; i < 4; ++i){
      const int rr = ((wv * 4 + i) << 3) + sr;
      gload_lds16(A  + (((size_t)(bm0 + rr)) << 9) + k0 + sc, (void*)&sA[bsel][(wv * 4 + i) * 512]);
      gload_lds16(Bt + (((size_t)(bn0 + rr)) << 9) + k0 + sc, (void*)&sB[bsel][(wv * 4 + i) * 512]);
    }
  };

  stage(0, 0);
  __syncthreads();
  int cur = 0;
  const int lr = lane & 15, lg = lane >> 4;

  for (int t = 0; t < 8; ++t){
    if (t < 7) stage(cur ^ 1, t + 1);
    const bf16x8* A8 = (const bf16x8*)sA[cur];
    const bf16x8* B8 = (const bf16x8*)sB[cur];
    #pragma unroll
    for (int ks = 0; ks < 2; ++ks){
      bf16x8 af[4], bg[4];
      #pragma unroll
      for (int mi = 0; mi < 4; ++mi)
        af[mi] = A8[((wm * 64 + mi * 16 + lr) << 3) + (ks << 2) + lg];
      #pragma unroll
      for (int ni = 0; ni < 4; ++ni)
        bg[ni] = B8[((wn * 64 + ni * 16 + lr) << 3) + (ks << 2) + lg];
      #pragma unroll
      for (int mi = 0; mi < 4; ++mi)
        #pragma unroll
        for (int ni = 0; ni < 4; ++ni)
          acc[mi][ni] = __builtin_amdgcn_mfma_f32_16x16x32_bf16(af[mi], bg[ni], acc[mi][ni], 0, 0, 0);
    }
    __syncthreads();
    cur ^= 1;
  }

  // epilogue: C/D layout col=lane&15, row=(lane>>4)*4+reg  [m89-verified]
  #pragma unroll
  for (int mi = 0; mi < 4; ++mi){
    const int row0 = bm0 + wm * 64 + mi * 16 + (lg << 2);
    #pragma unroll
    for (int ni = 0; ni < 4; ++ni){
      const int c0 = bn0 + wn * 64 + ni * 16 + lr;
      #pragma unroll
      for (int r = 0; r < 4; ++r)
        C[(((size_t)(row0 + r)) << 9) + c0] = f2bf(acc[mi][ni][r]);
    }
  }
}

// ---------------- aggregation: one wave per destination node ----------------

__global__ __launch_bounds__(256) void aggregate_kernel(const u32x4* __restrict__ h4,
                                                        const int* __restrict__ rowptr,
                                                        const int* __restrict__ col,
                                                        const float* __restrict__ dis,
                                                        const float* __restrict__ bias,
                                                        u32x4* __restrict__ xb4,
                                                        float* __restrict__ out,
                                                        int N, int last){
  const int lane = threadIdx.x & 63;
  const int v = blockIdx.x * 4 + (threadIdx.x >> 6);
  if (v >= N) return;

  const float dv = dis[v];
  float acc[8];
  {
    u32x4 q = h4[(size_t)v * 64 + lane]; // self loop, norm = dv*dv
    const float w = dv * dv;
    #pragma unroll
    for (int k = 0; k < 4; ++k){ acc[2*k] = w * bflo(q[k]); acc[2*k+1] = w * bfhi(q[k]); }
  }
  const int e1 = rowptr[v + 1];
  for (int e = rowptr[v]; e < e1; ++e){
    const int s = col[e];
    const float w = dis[s] * dv;
    u32x4 q = h4[(size_t)s * 64 + lane];
    #pragma unroll
    for (int k = 0; k < 4; ++k){ acc[2*k] += w * bflo(q[k]); acc[2*k+1] += w * bfhi(q[k]); }
  }

  const f32x4* b4 = (const f32x4*)bias;
  f32x4 b0 = b4[lane * 2], b1 = b4[lane * 2 + 1];
  #pragma unroll
  for (int j = 0; j < 4; ++j){ acc[j] += b0[j]; acc[4 + j] += b1[j]; }
  #pragma unroll
  for (int j = 0; j < 8; ++j) acc[j] = fmaxf(acc[j], 0.f);

  if (last){
    f32x4 t0 = {acc[0], acc[1], acc[2], acc[3]};
    f32x4 t1 = {acc[4], acc[5], acc[6], acc[7]};
    f32x4* o4 = (f32x4*)(out + (((size_t)v) << 9) + lane * 8);
    o4[0] = t0; o4[1] = t1;
  } else {
    u32x4 q;
    #pragma unroll
    for (int k = 0; k < 4; ++k)
      q[k] = ((u32)f2bf(acc[2*k+1]) << 16) | f2bf(acc[2*k]);
    xb4[(size_t)v * 64 + lane] = q;
  }
}

// ---------------- launch ----------------

extern "C" void kernel_launch(void* const* d_in, const int* in_sizes, int n_in,
                              void* d_out, int out_size, void* d_ws, size_t ws_size,
                              hipStream_t stream) {
  const float* x    = (const float*)d_in[0];
  const int*   ei   = (const int*)d_in[1];   // [2][E] int32: src = ei, dst = ei + E
  const float* W    = (const float*)d_in[2]; // [L][512][512]
  const float* bias = (const float*)d_in[3]; // [L][512]
  float* out = (float*)d_out;

  const int N = in_sizes[0] >> 9;       // 50000
  const int E = in_sizes[1] >> 1;       // 800000
  const int L = in_sizes[3] >> 9;       // 3
  const int MPAD = (N + 127) & ~127;    // 50048

  char* p = (char*)d_ws;
  auto alloc = [&](size_t bytes){ char* q = p; p += (bytes + 255) & ~(size_t)255; return q; };
  u16* xb      = (u16*)alloc((size_t)MPAD * 512 * 2);
  u16* hb      = (u16*)alloc((size_t)MPAD * 512 * 2);
  u16* wt      = (u16*)alloc((size_t)L * 512 * 512 * 2);
  float* dis   = (float*)alloc((size_t)N * 4);
  int* rowptr  = (int*)alloc((size_t)(N + 1) * 4);
  int* cursor  = (int*)alloc((size_t)N * 4);
  int* cnt     = (int*)alloc((size_t)N * 4);
  int* col     = (int*)alloc((size_t)E * 4);

  hipMemsetAsync(cnt, 0, (size_t)N * 4, stream);
  count_deg_kernel<<<(E + 255) / 256, 256, 0, stream>>>(ei + E, E, cnt);
  scan_kernel<<<1, 1024, 0, stream>>>(cnt, N, rowptr, cursor, dis);
  fill_csr_kernel<<<(E + 255) / 256, 256, 0, stream>>>(ei, ei + E, E, cursor, col);

  const int ntot = MPAD * 512;
  convert_x_kernel<<<(ntot / 8 + 255) / 256, 256, 0, stream>>>(x, (u32*)xb, N * 512, ntot);
  convert_w_kernel<<<(L * 512 * 512 + 255) / 256, 256, 0, stream>>>(W, wt, L * 512 * 512);

  for (int l = 0; l < L; ++l){
    gemm_kernel<<<dim3(MPAD / 128, 4), 256, 0, stream>>>(xb, wt + (size_t)l * 512 * 512, hb);
    aggregate_kernel<<<(N + 3) / 4, 256, 0, stream>>>((const u32x4*)hb, rowptr, col, dis,
                                                      bias + (size_t)l * 512, (u32x4*)xb, out,
                                                      N, (l == L - 1) ? 1 : 0);
  }
}

// Round 3
// 791.738 us; speedup vs baseline: 1.0122x; 1.0122x over previous
//
#include <hip/hip_runtime.h>
#include <hip/hip_bf16.h>

using u16 = unsigned short;
using u32 = unsigned int;

typedef __bf16 bf16x8 __attribute__((ext_vector_type(8)));
typedef float  f32x4  __attribute__((ext_vector_type(4)));
typedef u32    u32x4  __attribute__((ext_vector_type(4)));

__device__ __forceinline__ float bflo(u32 u){ union { u32 u; float f; } c; c.u = u << 16;          return c.f; }
__device__ __forceinline__ float bfhi(u32 u){ union { u32 u; float f; } c; c.u = u & 0xffff0000u;  return c.f; }
__device__ __forceinline__ u16  f2bf(float f){
  union { float f; u32 u; } c; c.f = f;
  u32 u = c.u;
  return (u16)((u + 0x7fffu + ((u >> 16) & 1u)) >> 16); // RNE
}

__device__ __forceinline__ void gload_lds16(const void* g, void* l){
  __builtin_amdgcn_global_load_lds(
      (const __attribute__((address_space(1))) void*)g,
      (__attribute__((address_space(3))) void*)l, 16, 0, 0);
}

// ---------------- prep: degree counts, hierarchical scan, CSR builds ----------------

__global__ void count_both_kernel(const int* __restrict__ ei, int E,
                                  int* __restrict__ cnt_s, int* __restrict__ cnt_d){
  int i = blockIdx.x * blockDim.x + threadIdx.x;
  if (i < E){
    atomicAdd(&cnt_s[ei[i]], 1);
    atomicAdd(&cnt_d[ei[E + i]], 1);
  }
}

// per-1024-block exclusive scan; block sums out
__global__ void scan1_kernel(const int* __restrict__ cnt, int n,
                             int* __restrict__ excl, int* __restrict__ bsums){
  __shared__ int sd[1024];
  const int tid = threadIdx.x;
  const int i = blockIdx.x * 1024 + tid;
  int v = (i < n) ? cnt[i] : 0;
  sd[tid] = v;
  __syncthreads();
  for (int s = 1; s < 1024; s <<= 1){
    int t = (tid >= s) ? sd[tid - s] : 0;
    __syncthreads();
    sd[tid] += t;
    __syncthreads();
  }
  if (i < n) excl[i] = sd[tid] - v;
  if (tid == 1023) bsums[blockIdx.x] = sd[tid];
}

// exclusive scan of block sums (nb <= 256), in place
__global__ void scan2_kernel(int* __restrict__ bsums, int nb){
  __shared__ int sd[256];
  const int tid = threadIdx.x;
  int v = (tid < nb) ? bsums[tid] : 0;
  sd[tid] = v;
  __syncthreads();
  for (int s = 1; s < 256; s <<= 1){
    int t = (tid >= s) ? sd[tid - s] : 0;
    __syncthreads();
    sd[tid] += t;
    __syncthreads();
  }
  if (tid < nb) bsums[tid] = sd[tid] - v;
}

__global__ void finalize_kernel(int* __restrict__ rowptr, int* __restrict__ cursor,
                                const int* __restrict__ bsums, const int* __restrict__ cnt,
                                float* __restrict__ dis, int n, int total){
  int i = blockIdx.x * blockDim.x + threadIdx.x;
  if (i < n){
    int r = rowptr[i] + bsums[i >> 10];
    rowptr[i] = r;
    cursor[i] = r;
    if (dis) dis[i] = rsqrtf((float)(cnt[i] + 1)); // +1 self loop
  }
  if (i == 0) rowptr[n] = total;
}

__global__ void fill_src_kernel(const int* __restrict__ ei, int E,
                                int* __restrict__ cursor_s, u16* __restrict__ srcadj){
  int i = blockIdx.x * blockDim.x + threadIdx.x;
  if (i < E){
    int s = ei[i];
    int p = atomicAdd(&cursor_s[s], 1);
    srcadj[p] = (u16)ei[E + i];
  }
}

// walk sources in ascending order -> each dst list filled ~sorted by src
__global__ void fill_dst_kernel(const int* __restrict__ rowptr_s, const u16* __restrict__ srcadj,
                                int N, int* __restrict__ cursor_d, u16* __restrict__ col){
  int s = blockIdx.x * blockDim.x + threadIdx.x;
  if (s >= N) return;
  const int p1 = rowptr_s[s + 1];
  for (int p = rowptr_s[s]; p < p1; ++p){
    int d = srcadj[p];
    int q = atomicAdd(&cursor_d[d], 1);
    col[q] = (u16)s;
  }
}

__global__ void convert_x_kernel(const float* __restrict__ x, u32* __restrict__ xb,
                                 int n_real, int n_tot){
  int i8 = (blockIdx.x * blockDim.x + threadIdx.x) * 8;
  if (i8 >= n_tot) return;
  u32 q0, q1, q2, q3;
  if (i8 < n_real){
    const f32x4* xp = (const f32x4*)(x + i8);
    f32x4 a = xp[0], b = xp[1];
    q0 = ((u32)f2bf(a[1]) << 16) | f2bf(a[0]);
    q1 = ((u32)f2bf(a[3]) << 16) | f2bf(a[2]);
    q2 = ((u32)f2bf(b[1]) << 16) | f2bf(b[0]);
    q3 = ((u32)f2bf(b[3]) << 16) | f2bf(b[2]);
  } else {
    q0 = q1 = q2 = q3 = 0u;
  }
  u32x4 q = {q0, q1, q2, q3};
  *(u32x4*)(xb + (i8 >> 1)) = q;
}

// Wt[l][n][k] = bf16(W[l][k][n])
__global__ void convert_w_kernel(const float* __restrict__ W, u16* __restrict__ Wt, int total){
  int i = blockIdx.x * blockDim.x + threadIdx.x;
  if (i >= total) return;
  int k = i & 511, n = (i >> 9) & 511, l = i >> 18;
  Wt[i] = f2bf(W[(l << 18) | (k << 9) | n]);
}

// ---------------- aggregation: agg[v] = dv^2*x[v] + sum_e dis[s]*dv*x[s]  (bf16 -> bf16) ----------------

__global__ __launch_bounds__(256) void aggregate_kernel(const u32x4* __restrict__ h4,
                                                        const int* __restrict__ rowptr,
                                                        const u16* __restrict__ col,
                                                        const float* __restrict__ dis,
                                                        u32x4* __restrict__ o4,
                                                        int N){
  const int lane = threadIdx.x & 63;
  const int v = blockIdx.x * 4 + (threadIdx.x >> 6);
  if (v >= N) return;

  const float dv = dis[v];
  float acc[8];
  {
    u32x4 q = h4[(size_t)v * 64 + lane]; // self loop, norm = dv*dv
    const float w = dv * dv;
    #pragma unroll
    for (int k = 0; k < 4; ++k){ acc[2*k] = w * bflo(q[k]); acc[2*k+1] = w * bfhi(q[k]); }
  }
  const int e0 = rowptr[v], e1 = rowptr[v + 1];
  int s_cur = 0; u32x4 qc = {0,0,0,0};
  if (e0 < e1){ s_cur = col[e0]; qc = h4[(size_t)s_cur * 64 + lane]; }
  for (int e = e0; e < e1; ++e){
    int s_nxt = 0; u32x4 qn = {0,0,0,0};
    if (e + 1 < e1){ s_nxt = col[e + 1]; qn = h4[(size_t)s_nxt * 64 + lane]; } // prefetch next row
    const float w = dis[s_cur] * dv;
    #pragma unroll
    for (int k = 0; k < 4; ++k){ acc[2*k] += w * bflo(qc[k]); acc[2*k+1] += w * bfhi(qc[k]); }
    s_cur = s_nxt; qc = qn;
  }

  u32x4 r;
  #pragma unroll
  for (int k = 0; k < 4; ++k)
    r[k] = ((u32)f2bf(acc[2*k+1]) << 16) | f2bf(acc[2*k]);
  o4[(size_t)v * 64 + lane] = r;
}

// ---------------- GEMM: C = relu(A * W + b), fused epilogue ----------------
// BM=BN=128, BK=64, 256 threads (4 waves, 2x2), double-buffered global_load_lds.

__global__ __launch_bounds__(256) void gemm_kernel(const u16* __restrict__ A,
                                                   const u16* __restrict__ Bt,
                                                   const float* __restrict__ bias,
                                                   u16* __restrict__ Cb,
                                                   float* __restrict__ Cf,
                                                   int n_real, int last){
  __shared__ u16 sA[2][128 * 64];
  __shared__ u16 sB[2][128 * 64];
  const int tid  = threadIdx.x;
  const int lane = tid & 63;
  const int wv   = tid >> 6;
  const int wm   = wv >> 1, wn = wv & 1;
  const int bm0  = blockIdx.x * 128;
  const int bn0  = blockIdx.y * 128;
  const int sr   = lane >> 3;
  const int sc   = (lane & 7) << 3;

  f32x4 acc[4][4] = {};

  auto stage = [&](int bsel, int t){
    const int k0 = t * 64;
    #pragma unroll
    for (int i = 0; i < 4; ++i){
      const int rr = ((wv * 4 + i) << 3) + sr;
      gload_lds16(A  + (((size_t)(bm0 + rr)) << 9) + k0 + sc, (void*)&sA[bsel][(wv * 4 + i) * 512]);
      gload_lds16(Bt + (((size_t)(bn0 + rr)) << 9) + k0 + sc, (void*)&sB[bsel][(wv * 4 + i) * 512]);
    }
  };

  stage(0, 0);
  __syncthreads();
  int cur = 0;
  const int lr = lane & 15, lg = lane >> 4;

  for (int t = 0; t < 8; ++t){
    if (t < 7) stage(cur ^ 1, t + 1);
    const bf16x8* A8 = (const bf16x8*)sA[cur];
    const bf16x8* B8 = (const bf16x8*)sB[cur];
    #pragma unroll
    for (int ks = 0; ks < 2; ++ks){
      bf16x8 af[4], bg[4];
      #pragma unroll
      for (int mi = 0; mi < 4; ++mi)
        af[mi] = A8[((wm * 64 + mi * 16 + lr) << 3) + (ks << 2) + lg];
      #pragma unroll
      for (int ni = 0; ni < 4; ++ni)
        bg[ni] = B8[((wn * 64 + ni * 16 + lr) << 3) + (ks << 2) + lg];
      #pragma unroll
      for (int mi = 0; mi < 4; ++mi)
        #pragma unroll
        for (int ni = 0; ni < 4; ++ni)
          acc[mi][ni] = __builtin_amdgcn_mfma_f32_16x16x32_bf16(af[mi], bg[ni], acc[mi][ni], 0, 0, 0);
    }
    __syncthreads();
    cur ^= 1;
  }

  // epilogue: C/D layout col=lane&15, row=(lane>>4)*4+reg  [m89-verified]
  float bb[4];
  #pragma unroll
  for (int ni = 0; ni < 4; ++ni) bb[ni] = bias[bn0 + wn * 64 + ni * 16 + lr];

  #pragma unroll
  for (int mi = 0; mi < 4; ++mi){
    const int row0 = bm0 + wm * 64 + mi * 16 + (lg << 2);
    #pragma unroll
    for (int ni = 0; ni < 4; ++ni){
      const int c0 = bn0 + wn * 64 + ni * 16 + lr;
      #pragma unroll
      for (int r = 0; r < 4; ++r){
        const float val = fmaxf(acc[mi][ni][r] + bb[ni], 0.f);
        if (!last){
          Cb[(((size_t)(row0 + r)) << 9) + c0] = f2bf(val);
        } else if (row0 + r < n_real){
          Cf[(((size_t)(row0 + r)) << 9) + c0] = val;
        }
      }
    }
  }
}

// ---------------- launch ----------------

extern "C" void kernel_launch(void* const* d_in, const int* in_sizes, int n_in,
                              void* d_out, int out_size, void* d_ws, size_t ws_size,
                              hipStream_t stream) {
  const float* x    = (const float*)d_in[0];
  const int*   ei   = (const int*)d_in[1];   // [2][E] int32: src = ei, dst = ei + E
  const float* W    = (const float*)d_in[2]; // [L][512][512]
  const float* bias = (const float*)d_in[3]; // [L][512]
  float* out = (float*)d_out;

  const int N = in_sizes[0] >> 9;       // 50000
  const int E = in_sizes[1] >> 1;       // 800000
  const int L = in_sizes[3] >> 9;       // 3
  const int MPAD = (N + 127) & ~127;    // 50048
  const int NB = (N + 1023) / 1024;     // scan blocks (49)

  char* p = (char*)d_ws;
  auto alloc = [&](size_t bytes){ char* q = p; p += (bytes + 255) & ~(size_t)255; return q; };
  u16*   xb       = (u16*)alloc((size_t)MPAD * 512 * 2);
  u16*   aggb     = (u16*)alloc((size_t)MPAD * 512 * 2);
  u16*   wt       = (u16*)alloc((size_t)L * 512 * 512 * 2);
  float* dis      = (float*)alloc((size_t)N * 4);
  int*   rowptr_d = (int*)alloc((size_t)(N + 1) * 4);
  int*   cursor_d = (int*)alloc((size_t)N * 4);
  int*   cnt_d    = (int*)alloc((size_t)N * 4);
  int*   rowptr_s = (int*)alloc((size_t)(N + 1) * 4);
  int*   cursor_s = (int*)alloc((size_t)N * 4);
  int*   cnt_s    = (int*)alloc((size_t)N * 4);
  u16*   srcadj   = (u16*)alloc((size_t)E * 2);
  u16*   col      = (u16*)alloc((size_t)E * 2);
  int*   bsums_d  = (int*)alloc(256 * 4);
  int*   bsums_s  = (int*)alloc(256 * 4);

  hipMemsetAsync(cnt_d, 0, (size_t)N * 4, stream);
  hipMemsetAsync(cnt_s, 0, (size_t)N * 4, stream);
  // zero the 48 pad rows of aggb once; aggregate only writes rows < N
  hipMemsetAsync(aggb + (size_t)N * 512, 0, (size_t)(MPAD - N) * 512 * 2, stream);

  count_both_kernel<<<(E + 255) / 256, 256, 0, stream>>>(ei, E, cnt_s, cnt_d);

  scan1_kernel<<<NB, 1024, 0, stream>>>(cnt_d, N, rowptr_d, bsums_d);
  scan1_kernel<<<NB, 1024, 0, stream>>>(cnt_s, N, rowptr_s, bsums_s);
  scan2_kernel<<<1, 256, 0, stream>>>(bsums_d, NB);
  scan2_kernel<<<1, 256, 0, stream>>>(bsums_s, NB);
  finalize_kernel<<<(N + 255) / 256, 256, 0, stream>>>(rowptr_d, cursor_d, bsums_d, cnt_d, dis, N, E);
  finalize_kernel<<<(N + 255) / 256, 256, 0, stream>>>(rowptr_s, cursor_s, bsums_s, cnt_s, (float*)nullptr, N, E);

  fill_src_kernel<<<(E + 255) / 256, 256, 0, stream>>>(ei, E, cursor_s, srcadj);
  fill_dst_kernel<<<(N + 255) / 256, 256, 0, stream>>>(rowptr_s, srcadj, N, cursor_d, col);

  const int ntot = MPAD * 512;
  convert_x_kernel<<<(ntot / 8 + 255) / 256, 256, 0, stream>>>(x, (u32*)xb, N * 512, ntot);
  convert_w_kernel<<<(L * 512 * 512 + 255) / 256, 256, 0, stream>>>(W, wt, L * 512 * 512);

  for (int l = 0; l < L; ++l){
    aggregate_kernel<<<(N + 3) / 4, 256, 0, stream>>>((const u32x4*)xb, rowptr_d, col, dis,
                                                      (u32x4*)aggb, N);
    gemm_kernel<<<dim3(MPAD / 128, 4), 256, 0, stream>>>(aggb, wt + (size_t)l * 512 * 512,
                                                         bias + (size_t)l * 512,
                                                         xb, out, N, (l == L - 1) ? 1 : 0);
  }
}